// Round 11
// baseline (85.635 us; speedup 1.0000x reference)
//
#include <hip/hip_runtime.h>
#include <hip/hip_bf16.h>

// dce_loss: out = concat(centers, sigma, -dist)
// -dist[b,i] = sum_k A[b,k]*W[i,k] + cn[i],  A=[bf16(x^2)|bf16(x)], W=[-sigma|2*sigma*c]
// GEMM 256x256, BK=64, 8 waves (verified best, r9: 67.9us, 1012 TF).
// A: ring-3 LDS (96KB), stage dist 2 tiles, slot^=(row&7). B: ring-3 half-tile
// LDS (48KB), slot=(q+(row>>1))&3. Both 0-conflict (r7-r9). Fragments
// prefetched one phase ahead in regs; vmcnt(6) + barrier at BOTH kk ends
// (minimum sync for this stage placement — r10's thinning raced, absmax 112).
// Preprocess merged into one launch (r10's safe piece).

#define B_SZ 8192
#define C_SZ 2048
#define D_SZ 1024
#define K2   2048

typedef __attribute__((ext_vector_type(4))) float f32x4;
typedef __attribute__((ext_vector_type(8))) short bf16x8;

static __device__ __forceinline__ unsigned short f2bf(float f) {
  union { float f; unsigned int u; } v; v.f = f;
  unsigned int r = v.u + 0x7fffu + ((v.u >> 16) & 1u);   // RNE, finite inputs
  return (unsigned short)(r >> 16);
}

// ---- merged preprocess ------------------------------------------------------
// blocks [0, 4096): A = [bf16(x^2) | bf16(x)]
// blocks [4096, 5120): per 2 classes: copy centers/sigma to out, W, cn
__global__ __launch_bounds__(256) void prep(const float* __restrict__ x,
                                            const float* __restrict__ centers,
                                            const float* __restrict__ sigma,
                                            unsigned short* __restrict__ Aop,
                                            float* __restrict__ out_centers,
                                            float* __restrict__ out_sigma,
                                            unsigned short* __restrict__ Wop,
                                            float* __restrict__ cn) {
  if (blockIdx.x < 4096) {
    const long t = (long)blockIdx.x * 256 + threadIdx.x;   // one per 8 elems
    const long e = t * 8;
    const long b = e >> 10;
    const int  d = (int)(e & 1023);
    const float4* xv = (const float4*)x;
    float4 v0 = xv[2 * t], v1 = xv[2 * t + 1];
    float vs[8] = {v0.x, v0.y, v0.z, v0.w, v1.x, v1.y, v1.z, v1.w};
    unsigned short sq[8] __attribute__((aligned(16)));
    unsigned short rw[8] __attribute__((aligned(16)));
#pragma unroll
    for (int j = 0; j < 8; ++j) {
      rw[j] = f2bf(vs[j]);
      sq[j] = f2bf(vs[j] * vs[j]);
    }
    *(uint4*)(Aop + b * K2 + d)        = *(uint4*)sq;
    *(uint4*)(Aop + b * K2 + D_SZ + d) = *(uint4*)rw;
  } else {
    const int grp = threadIdx.x >> 7;                        // 0..1
    const int i = (blockIdx.x - 4096) * 2 + grp;             // class
    const int t = threadIdx.x & 127;                         // 0..127
    const long base = (long)i * D_SZ;
    const float4* cv = (const float4*)(centers + base);
    const float4* sv = (const float4*)(sigma + base);
    float4 c0 = cv[2 * t], c1 = cv[2 * t + 1];
    float4 s0 = sv[2 * t], s1 = sv[2 * t + 1];
    ((float4*)(out_centers + base))[2 * t]     = c0;
    ((float4*)(out_centers + base))[2 * t + 1] = c1;
    ((float4*)(out_sigma + base))[2 * t]       = s0;
    ((float4*)(out_sigma + base))[2 * t + 1]   = s1;
    float cs[8] = {c0.x, c0.y, c0.z, c0.w, c1.x, c1.y, c1.z, c1.w};
    float ss[8] = {s0.x, s0.y, s0.z, s0.w, s1.x, s1.y, s1.z, s1.w};
    unsigned short w1[8] __attribute__((aligned(16)));
    unsigned short w2[8] __attribute__((aligned(16)));
    float p = 0.0f;
#pragma unroll
    for (int j = 0; j < 8; ++j) {
      w1[j] = f2bf(-ss[j]);
      w2[j] = f2bf(2.0f * ss[j] * cs[j]);
      p += ss[j] * cs[j] * cs[j];
    }
    *(uint4*)(Wop + (long)i * K2 + t * 8)        = *(uint4*)w1;
    *(uint4*)(Wop + (long)i * K2 + D_SZ + t * 8) = *(uint4*)w2;
#pragma unroll
    for (int off = 32; off > 0; off >>= 1) p += __shfl_down(p, off, 64);
    __shared__ float red[2][2];
    if ((t & 63) == 0) red[grp][t >> 6] = p;
    __syncthreads();
    if (t == 0) cn[i] = -(red[grp][0] + red[grp][1]);
  }
}

// ---- GEMM (byte-identical to round 9's verified gemm256) --------------------
#define VM6()  asm volatile("s_waitcnt vmcnt(6)" ::: "memory")
#define VM2()  asm volatile("s_waitcnt vmcnt(2)" ::: "memory")
#define VM0()  asm volatile("s_waitcnt vmcnt(0)" ::: "memory")
#define NOW()  ((void)0)
#define SB()   __builtin_amdgcn_sched_barrier(0)
#define BAR()  __builtin_amdgcn_s_barrier()

// A tile KT -> ring buf C (4 loads: 64 rows each)
#define STAGE_A(C, KT)                                                          \
  do {                                                                          \
    __builtin_amdgcn_global_load_lds(                                           \
        (__attribute__((address_space(1))) void*)(aS + 0 * 64 * (long)K2 + (long)(KT) * 64), \
        (__attribute__((address_space(3))) void*)(&As[C][0 * 4096 + dstE]), 16, 0, 0);       \
    __builtin_amdgcn_global_load_lds(                                           \
        (__attribute__((address_space(1))) void*)(aS + 1 * 64 * (long)K2 + (long)(KT) * 64), \
        (__attribute__((address_space(3))) void*)(&As[C][1 * 4096 + dstE]), 16, 0, 0);       \
    __builtin_amdgcn_global_load_lds(                                           \
        (__attribute__((address_space(1))) void*)(aS + 2 * 64 * (long)K2 + (long)(KT) * 64), \
        (__attribute__((address_space(3))) void*)(&As[C][2 * 4096 + dstE]), 16, 0, 0);       \
    __builtin_amdgcn_global_load_lds(                                           \
        (__attribute__((address_space(1))) void*)(aS + 3 * 64 * (long)K2 + (long)(KT) * 64), \
        (__attribute__((address_space(3))) void*)(&As[C][3 * 4096 + dstE]), 16, 0, 0);       \
  } while (0)

// B half (tile KT, k-half KK) -> half-ring buf C (2 loads: 128 rows each)
#define STAGE_B(C, KT, KK)                                                      \
  do {                                                                          \
    __builtin_amdgcn_global_load_lds(                                           \
        (__attribute__((address_space(1))) void*)(bS + 0 * 128 * (long)K2 + (long)(KT) * 64 + (KK) * 32), \
        (__attribute__((address_space(3))) void*)(&Bs[C][0 * 4096 + dstE]), 16, 0, 0);                    \
    __builtin_amdgcn_global_load_lds(                                           \
        (__attribute__((address_space(1))) void*)(bS + 1 * 128 * (long)K2 + (long)(KT) * 64 + (KK) * 32), \
        (__attribute__((address_space(3))) void*)(&Bs[C][1 * 4096 + dstE]), 16, 0, 0);                    \
  } while (0)

// fragment reads (swizzled, conflict-free: A verified r3+, B verified r7-r9)
#define LDA(BUF, KX, MI) (*(const bf16x8*)(&As[BUF][(aAddr ^ ((KX) * 32)) + (MI) * 1024]))
#define LDB(BUF, NI)     (*(const bf16x8*)(&Bs[BUF][bAddr + (NI) * 512]))

#define MM32(A0, A1, A2, A3, A4, A5, A6, A7, B0, B1, B2, B3)                     \
  acc[0][0] = __builtin_amdgcn_mfma_f32_16x16x32_bf16(A0, B0, acc[0][0], 0,0,0); \
  acc[0][1] = __builtin_amdgcn_mfma_f32_16x16x32_bf16(A0, B1, acc[0][1], 0,0,0); \
  acc[0][2] = __builtin_amdgcn_mfma_f32_16x16x32_bf16(A0, B2, acc[0][2], 0,0,0); \
  acc[0][3] = __builtin_amdgcn_mfma_f32_16x16x32_bf16(A0, B3, acc[0][3], 0,0,0); \
  acc[1][0] = __builtin_amdgcn_mfma_f32_16x16x32_bf16(A1, B0, acc[1][0], 0,0,0); \
  acc[1][1] = __builtin_amdgcn_mfma_f32_16x16x32_bf16(A1, B1, acc[1][1], 0,0,0); \
  acc[1][2] = __builtin_amdgcn_mfma_f32_16x16x32_bf16(A1, B2, acc[1][2], 0,0,0); \
  acc[1][3] = __builtin_amdgcn_mfma_f32_16x16x32_bf16(A1, B3, acc[1][3], 0,0,0); \
  acc[2][0] = __builtin_amdgcn_mfma_f32_16x16x32_bf16(A2, B0, acc[2][0], 0,0,0); \
  acc[2][1] = __builtin_amdgcn_mfma_f32_16x16x32_bf16(A2, B1, acc[2][1], 0,0,0); \
  acc[2][2] = __builtin_amdgcn_mfma_f32_16x16x32_bf16(A2, B2, acc[2][2], 0,0,0); \
  acc[2][3] = __builtin_amdgcn_mfma_f32_16x16x32_bf16(A2, B3, acc[2][3], 0,0,0); \
  acc[3][0] = __builtin_amdgcn_mfma_f32_16x16x32_bf16(A3, B0, acc[3][0], 0,0,0); \
  acc[3][1] = __builtin_amdgcn_mfma_f32_16x16x32_bf16(A3, B1, acc[3][1], 0,0,0); \
  acc[3][2] = __builtin_amdgcn_mfma_f32_16x16x32_bf16(A3, B2, acc[3][2], 0,0,0); \
  acc[3][3] = __builtin_amdgcn_mfma_f32_16x16x32_bf16(A3, B3, acc[3][3], 0,0,0); \
  acc[4][0] = __builtin_amdgcn_mfma_f32_16x16x32_bf16(A4, B0, acc[4][0], 0,0,0); \
  acc[4][1] = __builtin_amdgcn_mfma_f32_16x16x32_bf16(A4, B1, acc[4][1], 0,0,0); \
  acc[4][2] = __builtin_amdgcn_mfma_f32_16x16x32_bf16(A4, B2, acc[4][2], 0,0,0); \
  acc[4][3] = __builtin_amdgcn_mfma_f32_16x16x32_bf16(A4, B3, acc[4][3], 0,0,0); \
  acc[5][0] = __builtin_amdgcn_mfma_f32_16x16x32_bf16(A5, B0, acc[5][0], 0,0,0); \
  acc[5][1] = __builtin_amdgcn_mfma_f32_16x16x32_bf16(A5, B1, acc[5][1], 0,0,0); \
  acc[5][2] = __builtin_amdgcn_mfma_f32_16x16x32_bf16(A5, B2, acc[5][2], 0,0,0); \
  acc[5][3] = __builtin_amdgcn_mfma_f32_16x16x32_bf16(A5, B3, acc[5][3], 0,0,0); \
  acc[6][0] = __builtin_amdgcn_mfma_f32_16x16x32_bf16(A6, B0, acc[6][0], 0,0,0); \
  acc[6][1] = __builtin_amdgcn_mfma_f32_16x16x32_bf16(A6, B1, acc[6][1], 0,0,0); \
  acc[6][2] = __builtin_amdgcn_mfma_f32_16x16x32_bf16(A6, B2, acc[6][2], 0,0,0); \
  acc[6][3] = __builtin_amdgcn_mfma_f32_16x16x32_bf16(A6, B3, acc[6][3], 0,0,0); \
  acc[7][0] = __builtin_amdgcn_mfma_f32_16x16x32_bf16(A7, B0, acc[7][0], 0,0,0); \
  acc[7][1] = __builtin_amdgcn_mfma_f32_16x16x32_bf16(A7, B1, acc[7][1], 0,0,0); \
  acc[7][2] = __builtin_amdgcn_mfma_f32_16x16x32_bf16(A7, B2, acc[7][2], 0,0,0); \
  acc[7][3] = __builtin_amdgcn_mfma_f32_16x16x32_bf16(A7, B3, acc[7][3], 0,0,0);

// One K-tile U. kk0: MFMA(aP,bP) || prefetch aQ<-A(U,kk1), bQ<-B half h+1 ||
// stage B(U+1,h1)->BS0, A(U+2)->AST.  kk1: MFMA(aQ,bQ) || prefetch
// aP<-A(U+1,kk0), bP<-B half h+2 || stage B(U+2,h0)->BS1.
#define TILE(AC, AN, AST, P1, P2, BS0, BS1, U, STGA, SB0_, SB1_, W0, W1, PRE)  \
  { /* kk0 */                                                                  \
    if (SB0_) STAGE_B(BS0, (U) + 1, 1);                                        \
    if (STGA) STAGE_A(AST, (U) + 2);                                           \
    aQ0 = LDA(AC, 1, 0); aQ1 = LDA(AC, 1, 1);                                  \
    aQ2 = LDA(AC, 1, 2); aQ3 = LDA(AC, 1, 3);                                  \
    aQ4 = LDA(AC, 1, 4); aQ5 = LDA(AC, 1, 5);                                  \
    aQ6 = LDA(AC, 1, 6); aQ7 = LDA(AC, 1, 7);                                  \
    bQ0 = LDB(P1, 0); bQ1 = LDB(P1, 1); bQ2 = LDB(P1, 2); bQ3 = LDB(P1, 3);    \
    MM32(aP0, aP1, aP2, aP3, aP4, aP5, aP6, aP7, bP0, bP1, bP2, bP3)           \
    SB(); W0(); SB(); BAR();                                                   \
  }                                                                            \
  { /* kk1 */                                                                  \
    if (SB1_) STAGE_B(BS1, (U) + 2, 0);                                        \
    if (PRE) {                                                                 \
      aP0 = LDA(AN, 0, 0); aP1 = LDA(AN, 0, 1);                                \
      aP2 = LDA(AN, 0, 2); aP3 = LDA(AN, 0, 3);                                \
      aP4 = LDA(AN, 0, 4); aP5 = LDA(AN, 0, 5);                                \
      aP6 = LDA(AN, 0, 6); aP7 = LDA(AN, 0, 7);                                \
      bP0 = LDB(P2, 0); bP1 = LDB(P2, 1); bP2 = LDB(P2, 2); bP3 = LDB(P2, 3);  \
    }                                                                          \
    MM32(aQ0, aQ1, aQ2, aQ3, aQ4, aQ5, aQ6, aQ7, bQ0, bQ1, bQ2, bQ3)          \
    SB(); W1(); SB(); BAR();                                                   \
  }

__global__ __launch_bounds__(512, 2) void gemm256(const unsigned short* __restrict__ A,
                                                  const unsigned short* __restrict__ W,
                                                  const float* __restrict__ cn,
                                                  float* __restrict__ out) {
  // A: ring-3 [3][256 rows][64 k], phys 16B-slot = logical ^ (row&7)       (96KB)
  // B: half-ring-3 [3][256 rows][32 k], phys slot = (logical + (row>>1))&3 (48KB)
  __shared__ __attribute__((aligned(16))) unsigned short As[3][16384];
  __shared__ __attribute__((aligned(16))) unsigned short Bs[3][8192];

  const int tid  = threadIdx.x;
  const int lane = tid & 63;
  const int wave = tid >> 6;
  const int wr = wave >> 2;              // 0..1 -> 128-row half of M
  const int wc = wave & 3;               // 0..3 -> 64-row slice of N

  // XCD-aware block swizzle: xcd owns 4 m-panels x 8 n-tiles
  const int bid = blockIdx.x;
  const int xcd = bid & 7, idx = bid >> 3;
  const long rowBase = (long)(xcd * 4 + (idx >> 3)) * 256;
  const long colBase = (long)(idx & 7) * 256;

  // A staging: rows (tid>>3)+{0,64,128,192}; phys slot tid&7 <- logical (tid&7)^(row&7)
  const int sr = tid >> 3;
  const int sl = (tid & 7) ^ (sr & 7);
  const unsigned short* aS = A + (rowBase + sr) * (long)K2 + sl * 8;
  // B staging: rows (tid>>2)+{0,128}; phys slot tid&3 <- logical ((tid&3)-(row>>1))&3
  const int br = tid >> 2;
  const int bl = ((tid & 3) - (tid >> 3)) & 3;
  const unsigned short* bS = W + (colBase + br) * (long)K2 + bl * 8;
  const int dstE = tid * 8;

  // fragment read bases
  const int l15 = lane & 15, l7 = lane & 7, q = lane >> 4;
  const int aAddr = (wr * 128 + l15) * 64 + ((q ^ l7) * 8);        // kk0; kk1 = ^32
  const int bAddr = (wc * 64 + l15) * 32 + (((q + (l15 >> 1)) & 3) * 8);

  f32x4 acc[8][4];
#pragma unroll
  for (int i = 0; i < 8; ++i)
#pragma unroll
    for (int j = 0; j < 4; ++j) acc[i][j] = (f32x4){0.f, 0.f, 0.f, 0.f};

  bf16x8 aP0, aP1, aP2, aP3, aP4, aP5, aP6, aP7;
  bf16x8 aQ0, aQ1, aQ2, aQ3, aQ4, aQ5, aQ6, aQ7;
  bf16x8 bP0, bP1, bP2, bP3, bQ0, bQ1, bQ2, bQ3;

  // prologue: A(0)->0, Bh0->0, Bh1->1, A(1)->1, Bh2->2  (14 loads)
  STAGE_A(0, 0);
  STAGE_B(0, 0, 0);
  STAGE_B(1, 0, 1);
  STAGE_A(1, 1);
  STAGE_B(2, 1, 0);
  VM6(); SB(); BAR();   // A0,Bh0,Bh1 landed; A1,Bh2 in flight
  // preload phase-0 fragments
  aP0 = LDA(0, 0, 0); aP1 = LDA(0, 0, 1); aP2 = LDA(0, 0, 2); aP3 = LDA(0, 0, 3);
  aP4 = LDA(0, 0, 4); aP5 = LDA(0, 0, 5); aP6 = LDA(0, 0, 6); aP7 = LDA(0, 0, 7);
  bP0 = LDB(0, 0); bP1 = LDB(0, 1); bP2 = LDB(0, 2); bP3 = LDB(0, 3);

  // tiles 0..29: period 3  (B buf for half h = h%3; A buf for tile t = t%3)
#pragma unroll 1
  for (int u = 0; u < 30; u += 3) {
    TILE(0, 1, 2, 1, 2, 0, 1, u + 0, 1, 1, 1, VM6, VM6, 1);
    TILE(1, 2, 0, 0, 1, 2, 0, u + 1, 1, 1, 1, VM6, VM6, 1);
    TILE(2, 0, 1, 2, 0, 1, 2, u + 2, 1, 1, 1, VM6, VM6, 1);
  }
  // tail: tile 30 (stage only B(31,k1)), tile 31 (no stages, no final prefetch)
  TILE(0, 1, 2, 1, 2, 0, 1, 30, 0, 1, 0, VM2, VM0, 1);
  TILE(1, 2, 0, 0, 1, 2, 0, 31, 0, 0, 0, NOW, NOW, 0);

  // epilogue: C/D layout col=lane&15, row=(lane>>4)*4+j (m89-verified)
  const int crow = (lane >> 4) * 4;
  const int ccol = lane & 15;
#pragma unroll
  for (int ni = 0; ni < 4; ++ni) {
    const long col = colBase + wc * 64 + ni * 16 + ccol;
    const float c = cn[col];
#pragma unroll
    for (int mi = 0; mi < 8; ++mi) {
      const long row = rowBase + wr * 128 + mi * 16 + crow;
      float* o = out + row * C_SZ + col;
#pragma unroll
      for (int j = 0; j < 4; ++j) o[(long)j * C_SZ] = acc[mi][ni][j] + c;
    }
  }
}

extern "C" void kernel_launch(void* const* d_in, const int* in_sizes, int n_in,
                              void* d_out, int out_size, void* d_ws, size_t ws_size,
                              hipStream_t stream) {
  const float* x       = (const float*)d_in[0];
  const float* centers = (const float*)d_in[1];
  const float* sigma   = (const float*)d_in[2];
  float* out = (float*)d_out;

  unsigned short* Aop = (unsigned short*)d_ws;            // 8192*2048 bf16
  unsigned short* Wop = Aop + (long)B_SZ * K2;            // 2048*2048 bf16
  float* cnp = (float*)(Wop + (long)C_SZ * K2);           // 2048 f32

  prep<<<4096 + 1024, 256, 0, stream>>>(x, centers, sigma, Aop,
                                        out, out + (size_t)C_SZ * D_SZ, Wop, cnp);

  float* out2 = out + (size_t)2 * C_SZ * D_SZ;
  gemm256<<<256, 512, 0, stream>>>(Aop, Wop, cnp, out2);
}